// Round 9
// baseline (72.946 us; speedup 1.0000x reference)
//
#include <hip/hip_runtime.h>
#include <math.h>

// PHOSA interaction loss, MI355X — round 9: round-6/8 fused kernel with the
// object stream vectorized to float4 (16 B/lane). Scalar-dword streaming was
// the 2x-off-BW culprit (Guideline 13). smpl batch base is only 4B-aligned
// (10475*3*4 B), so smpl stays scalar (14% of bytes, overlapped).
// Gather roles are byte-identical to round 6/8 -> loss_parts bitwise same;
// only obj batch-sum association order changes (loss_inter +- ~1e-10).
constexpr int B_   = 256;
constexpr int NS_  = 10475;
constexpr int NO_  = 65536;
constexpr int P_   = 8;
constexpr int KS_  = 1024;
constexpr int KO_  = 2048;
constexpr int NBLK_S = 4;    // stream blocks per batch, smpl
constexpr int NBLK_O = 16;   // stream blocks per batch, object (4096 verts)
constexpr float EPS_ = 1e-9f;
constexpr float ZTH_ = 5.0f;

// per-batch work units: 16 objsum + 8 objgather + 4 smplsum + 8 smplgather
constexpr int UNITS_PER_B = NBLK_O + P_ + NBLK_S + P_;   // 36
constexpr int NXCD = 8;
constexpr int NSLOT = B_ / NXCD;                         // 32

#define DEV_INLINE __device__ __forceinline__

DEV_INLINE float wredsum(float v) {
#pragma unroll
    for (int o = 32; o; o >>= 1) v += __shfl_down(v, o);
    return v;
}
DEV_INLINE float wredmin(float v) {
#pragma unroll
    for (int o = 32; o; o >>= 1) v = fminf(v, __shfl_down(v, o));
    return v;
}
DEV_INLINE float wredmax(float v) {
#pragma unroll
    for (int o = 32; o; o >>= 1) v = fmaxf(v, __shfl_down(v, o));
    return v;
}

// ---------------------------------------------------------------------------
// Object stream role: float4-vectorized batch component partial sums.
// Chunk = 4096 verts = 12288 floats = 3072 float4s; 256 threads x 12 float4.
// Thread t, iter j handles 4-vertex group g = j*256 + t:
//   f0=(x0,y0,z0,x1) f1=(y1,z1,x2,y2) f2=(z2,x3,y3,z3).
// ---------------------------------------------------------------------------
DEV_INLINE void batch_sum_obj_body(const float* __restrict__ v, int b, int blk,
                                   float* __restrict__ out) {
    const float4* base = reinterpret_cast<const float4*>(
        v + (size_t)b * NO_ * 3 + (size_t)blk * 4096 * 3);
    const int t = threadIdx.x;
    float4 f[12];
#pragma unroll
    for (int j = 0; j < 4; ++j) {
        const int g = j * 256 + t;
#pragma unroll
        for (int q = 0; q < 3; ++q) f[j * 3 + q] = base[g * 3 + q];
    }
    float sx = 0.f, sy = 0.f, sz = 0.f;
#pragma unroll
    for (int j = 0; j < 4; ++j) {
        const float4 f0 = f[j * 3 + 0], f1 = f[j * 3 + 1], f2 = f[j * 3 + 2];
        sx += f0.x + f0.w + f1.z + f2.y;
        sy += f0.y + f1.x + f1.w + f2.z;
        sz += f0.z + f1.y + f2.x + f2.w;
    }
    __shared__ float red[3][4];
    const float r0 = wredsum(sx), r1 = wredsum(sy), r2 = wredsum(sz);
    const int lane = t & 63, wv = t >> 6;
    if (lane == 0) { red[0][wv] = r0; red[1][wv] = r1; red[2][wv] = r2; }
    __syncthreads();
    if (t == 0) {
        float* o = out + ((size_t)b * NBLK_O + blk) * 3;
        o[0] = red[0][0] + red[0][1] + red[0][2] + red[0][3];
        o[1] = red[1][0] + red[1][1] + red[1][2] + red[1][3];
        o[2] = red[2][0] + red[2][1] + red[2][2] + red[2][3];
    }
}

// ---------------------------------------------------------------------------
// smpl stream role: scalar partial sums (verbatim round-6; base only 4B-aligned).
// ---------------------------------------------------------------------------
DEV_INLINE void batch_sum_smpl_body(const float* __restrict__ v, int b, int blk,
                                    float* __restrict__ out) {
    constexpr int chunk = (NS_ + NBLK_S - 1) / NBLK_S;
    const int s = blk * chunk;
    const int e = min(NS_, s + chunk);
    const float* base = v + (size_t)b * NS_ * 3;
    float sx = 0.f, sy = 0.f, sz = 0.f;
    for (int i = s + (int)threadIdx.x; i < e; i += 256) {
        const float* p = base + (size_t)i * 3;
        sx += p[0];
        sy += p[1];
        sz += p[2];
    }
    __shared__ float red[3][4];
    float r0 = wredsum(sx), r1 = wredsum(sy), r2 = wredsum(sz);
    const int lane = threadIdx.x & 63, wv = threadIdx.x >> 6;
    if (lane == 0) { red[0][wv] = r0; red[1][wv] = r1; red[2][wv] = r2; }
    __syncthreads();
    if (threadIdx.x == 0) {
        float* o = out + ((size_t)b * NBLK_S + blk) * 3;
        o[0] = red[0][0] + red[0][1] + red[0][2] + red[0][3];
        o[1] = red[1][0] + red[1][1] + red[1][2] + red[1][3];
        o[2] = red[2][0] + red[2][1] + red[2][2] + red[2][3];
    }
}

// ---------------------------------------------------------------------------
// Gather role: per-(batch,part) statistics (byte-identical to round 6/8).
// ---------------------------------------------------------------------------
template <int N, int K>
DEV_INLINE void part_stats_body(const float* __restrict__ v,
                                const int* __restrict__ pidx,
                                const float* __restrict__ Ks, int b, int p,
                                float* __restrict__ out) {
    const float fx = Ks[b * 9 + 0];
    const float cx = Ks[b * 9 + 2];
    const float fy = Ks[b * 9 + 4];
    const float cy = Ks[b * 9 + 5];
    const float* base = v + (size_t)b * N * 3;
    const int* idx = pidx + (size_t)p * K;

    constexpr int ITER = K / 256;
    int ids[ITER];
#pragma unroll
    for (int j = 0; j < ITER; ++j) ids[j] = idx[threadIdx.x + j * 256];

    float vx[ITER], vy[ITER], vz[ITER];
#pragma unroll
    for (int j = 0; j < ITER; ++j) {
        const float* vp = base + (size_t)ids[j] * 3;
        vx[j] = vp[0]; vy[j] = vp[1]; vz[j] = vp[2];
    }

    float umin = INFINITY, umax = -INFINITY, wmin = INFINITY, wmax = -INFINITY;
    float zmin = INFINITY, zmax = -INFINITY;
    float sx = 0.f, sy = 0.f, sz = 0.f;
#pragma unroll
    for (int j = 0; j < ITER; ++j) {
        const float x = vx[j], y = vy[j], z = vz[j];
        sx += x; sy += y; sz += z;
        zmin = fminf(zmin, z); zmax = fmaxf(zmax, z);
        float u, w;
        {
#pragma clang fp contract(off)
            const float zd = z + EPS_;
            const float x_ = x / zd;
            const float y_ = (-y) / zd;
            u = fx * x_ + cx;
            w = 1.0f - (fy * y_ + cy);
            u = 2.0f * (u - 0.5f);
            w = 2.0f * (w - 0.5f);
        }
        umin = fminf(umin, u); umax = fmaxf(umax, u);
        wmin = fminf(wmin, w); wmax = fmaxf(wmax, w);
    }

    __shared__ float red[4][9];
    float r[9];
    r[0] = wredmin(umin); r[1] = wredmax(umax);
    r[2] = wredmin(wmin); r[3] = wredmax(wmax);
    r[4] = wredmin(zmin); r[5] = wredmax(zmax);
    r[6] = wredsum(sx);   r[7] = wredsum(sy); r[8] = wredsum(sz);
    const int lane = threadIdx.x & 63, wv = threadIdx.x >> 6;
    if (lane == 0) {
#pragma unroll
        for (int q = 0; q < 9; ++q) red[wv][q] = r[q];
    }
    __syncthreads();
    if (threadIdx.x == 0) {
        float* o = out + ((size_t)b * P_ + p) * 9;
        o[0] = fminf(fminf(red[0][0], red[1][0]), fminf(red[2][0], red[3][0]));
        o[1] = fmaxf(fmaxf(red[0][1], red[1][1]), fmaxf(red[2][1], red[3][1]));
        o[2] = fminf(fminf(red[0][2], red[1][2]), fminf(red[2][2], red[3][2]));
        o[3] = fmaxf(fmaxf(red[0][3], red[1][3]), fmaxf(red[2][3], red[3][3]));
        o[4] = fminf(fminf(red[0][4], red[1][4]), fminf(red[2][4], red[3][4]));
        o[5] = fmaxf(fmaxf(red[0][5], red[1][5]), fmaxf(red[2][5], red[3][5]));
        o[6] = red[0][6] + red[1][6] + red[2][6] + red[3][6];
        o[7] = red[0][7] + red[1][7] + red[2][7] + red[3][7];
        o[8] = red[0][8] + red[1][8] + red[2][8] + red[3][8];
    }
}

// ---------------------------------------------------------------------------
// Phase 1: gid -> xcd = gid&7, unit = gid>>3, slot = unit/36, role = unit%36.
// Stream roles use batch slot*8+xcd; gather roles use the previous slot's
// batch (kept from round 8; neutral but harmless).
// role: [0,16) objsum | [16,24) objgather | [24,28) smplsum | [28,36) smplgather
// ---------------------------------------------------------------------------
__global__ __launch_bounds__(256) void phase1_kernel(
        const float* __restrict__ obj, const float* __restrict__ smpl,
        const float* __restrict__ Ks,
        const int* __restrict__ sidx, const int* __restrict__ oidx,
        float* __restrict__ sumO, float* __restrict__ sumS,
        float* __restrict__ statsO, float* __restrict__ statsS) {
    const int gid = blockIdx.x;
    const int xcd = gid & (NXCD - 1);
    const int unit = gid >> 3;
    const int slot = unit / UNITS_PER_B;
    const int role = unit % UNITS_PER_B;
    const int bs = slot * NXCD + xcd;                        // stream batch
    const int bg = ((slot + NSLOT - 1) & (NSLOT - 1)) * NXCD + xcd; // gather batch
    if (role < NBLK_O) {
        batch_sum_obj_body(obj, bs, role, sumO);
    } else if (role < NBLK_O + P_) {
        part_stats_body<NO_, KO_>(obj, oidx, Ks, bg, role - NBLK_O, statsO);
    } else if (role < NBLK_O + P_ + NBLK_S) {
        batch_sum_smpl_body(smpl, bs, role - (NBLK_O + P_), sumS);
    } else {
        part_stats_body<NS_, KS_>(smpl, sidx, Ks, bg, role - (NBLK_O + P_ + NBLK_S), statsS);
    }
}

// ---------------------------------------------------------------------------
// Kernel D: per-batch pair masking + partial sums (verbatim round-2/6/8).
// ---------------------------------------------------------------------------
__global__ __launch_bounds__(64) void pair_kernel(
        const float* __restrict__ statsS, const float* __restrict__ statsO,
        float* __restrict__ partial) {
#pragma clang fp contract(off)
    const int b = blockIdx.x;
    __shared__ float sS[P_][9];
    __shared__ float sO[P_][9];
    const int t = threadIdx.x;
    for (int i = t; i < 2 * P_ * 9; i += 64) {
        if (i < P_ * 9) sS[i / 9][i % 9] = statsS[(size_t)b * P_ * 9 + i];
        else {
            const int u = i - P_ * 9;
            sO[u / 9][u % 9] = statsO[(size_t)b * P_ * 9 + u];
        }
    }
    __syncthreads();

    const int ps = t >> 3;
    const int po = t & 7;

    const float* ssp = sS[po];
    const float* sop = sO[po];
    const float pcu = (ssp[0] + ssp[1]) * 0.5f;
    const float phu = (ssp[1] - ssp[0]) * 0.5f * 1.5f;
    const float pcw = (ssp[2] + ssp[3]) * 0.5f;
    const float phw = (ssp[3] - ssp[2]) * 0.5f * 1.5f;
    const float px0 = pcu - phu, px1 = pcu + phu;
    const float py0 = pcw - phw, py1 = pcw + phw;
    const float ocu = (sop[0] + sop[1]) * 0.5f;
    const float ohu = (sop[1] - sop[0]) * 0.5f * 1.5f;
    const float ocw = (sop[2] + sop[3]) * 0.5f;
    const float ohw = (sop[3] - sop[2]) * 0.5f * 1.5f;
    const float ox0 = ocu - ohu, ox1 = ocu + ohu;
    const float oy0 = ocw - ohw, oy1 = ocw + ohw;
    const bool ov = !((ox0 > px1) || (px0 > ox1) || (oy0 > py1) || (py0 > oy1));

    const float a  = sS[ps][4];
    const float bm = sS[ps][5];
    const float c  = sO[po][4];
    const float d  = sO[po][5];
    const float gap = fminf(fabsf(c - bm), fabsf(a - d));
    const float zd = ((d >= a) && (bm >= c)) ? 0.f : gap;
    const bool m = ov && (zd < ZTH_);

    const float ms0 = sS[ps][6] / (float)KS_;
    const float ms1 = sS[ps][7] / (float)KS_;
    const float ms2 = sS[ps][8] / (float)KS_;
    const float mo0 = sO[po][6] / (float)KO_;
    const float mo1 = sO[po][7] / (float)KO_;
    const float mo2 = sO[po][8] / (float)KO_;
    const float d0 = ms0 - mo0, d1 = ms1 - mo1, d2 = ms2 - mo2;
    const float pm = (d0 * d0 + d1 * d1 + d2 * d2) / 3.0f;

    float psum = m ? pm : 0.f;
    float pcnt = m ? 1.f : 0.f;
    psum = wredsum(psum);
    pcnt = wredsum(pcnt);
    if (t == 0) {
        partial[(size_t)b * 2 + 0] = psum;
        partial[(size_t)b * 2 + 1] = pcnt;
    }
}

// ---------------------------------------------------------------------------
// Kernel E: loss_inter + final reduce (verbatim round-6/8).
// ---------------------------------------------------------------------------
__global__ __launch_bounds__(256) void last_kernel(
        const float* __restrict__ sumS, const float* __restrict__ sumO,
        const float* __restrict__ pairPartial, float* __restrict__ out) {
    const int t = threadIdx.x;
    float d2 = 0.f;
#pragma unroll
    for (int c = 0; c < 3; ++c) {
        float ss = 0.f, so = 0.f;
#pragma unroll
        for (int k = 0; k < NBLK_S; ++k) ss += sumS[((size_t)t * NBLK_S + k) * 3 + c];
#pragma unroll
        for (int k = 0; k < NBLK_O; ++k) so += sumO[((size_t)t * NBLK_O + k) * 3 + c];
        const float ms = ss / (float)NS_;
        const float mo = so / (float)NO_;
        const float d = ms - mo;
        d2 += d * d;
    }
    float s = pairPartial[(size_t)t * 2 + 0];
    float c2 = pairPartial[(size_t)t * 2 + 1];
    __shared__ float rli[4], rs[4], rc[4];
    const float rl = wredsum(d2);
    const float ss2 = wredsum(s);
    const float cc = wredsum(c2);
    const int lane = t & 63, wv = t >> 6;
    if (lane == 0) { rli[wv] = rl; rs[wv] = ss2; rc[wv] = cc; }
    __syncthreads();
    if (t == 0) {
        const float tot = rli[0] + rli[1] + rli[2] + rli[3];
        out[0] = tot / (3.0f * (float)B_) / (float)B_;
        const float S = rs[0] + rs[1] + rs[2] + rs[3];
        const float C = rc[0] + rc[1] + rc[2] + rc[3];
        out[1] = (C > 0.f) ? (S / C) : 0.f;
    }
}

// ---------------------------------------------------------------------------
extern "C" void kernel_launch(void* const* d_in, const int* in_sizes, int n_in,
                              void* d_out, int out_size, void* d_ws, size_t ws_size,
                              hipStream_t stream) {
    const float* smpl = (const float*)d_in[0];
    const float* obj  = (const float*)d_in[1];
    const float* Ks   = (const float*)d_in[2];
    const int*   sidx = (const int*)d_in[3];
    const int*   oidx = (const int*)d_in[4];
    float* out = (float*)d_out;

    float* w = (float*)d_ws;
    float* sumO   = w;                                 // 256*16*3 = 12288
    float* sumS   = sumO + (size_t)B_ * NBLK_O * 3;    // 256*4*3  = 3072
    float* statsS = sumS + (size_t)B_ * NBLK_S * 3;    // 256*8*9  = 18432
    float* statsO = statsS + (size_t)B_ * P_ * 9;      // 256*8*9  = 18432
    float* pairP  = statsO + (size_t)B_ * P_ * 9;      // 512

    phase1_kernel<<<B_ * UNITS_PER_B, 256, 0, stream>>>(
        obj, smpl, Ks, sidx, oidx, sumO, sumS, statsO, statsS);
    pair_kernel<<<B_, 64, 0, stream>>>(statsS, statsO, pairP);
    last_kernel<<<1, 256, 0, stream>>>(sumS, sumO, pairP, out);
}

// Round 10
// 69.631 us; speedup vs baseline: 1.0476x; 1.0476x over previous
//
#include <hip/hip_runtime.h>
#include <math.h>

// PHOSA interaction loss, MI355X — round 10: round-8 fused kernel (68.8 us,
// absmax 0.0) with ONE change: gather loads each vertex as a single 16 B
// dword-aligned vector load (global_load_dwordx4) instead of 3 scalar dwords.
// Random-index wave loads hit 64 distinct lines, so each load costs ~64
// address slots in the L1/TA pipe; 3->1 loads per vertex cuts the gather's
// address-pipe occupancy ~3x (the round-6..9 latency-bound signature:
// HBM 20%, VALU 12%, occ 76%). Values and accumulation order are bitwise
// identical; the global-last vertex uses a shifted load + component select.
constexpr int B_   = 256;
constexpr int NS_  = 10475;
constexpr int NO_  = 65536;
constexpr int P_   = 8;
constexpr int KS_  = 1024;
constexpr int KO_  = 2048;
constexpr int NBLK_S = 4;    // stream blocks per batch, smpl
constexpr int NBLK_O = 16;   // stream blocks per batch, object
constexpr float EPS_ = 1e-9f;
constexpr float ZTH_ = 5.0f;

// per-batch work units: 16 objsum + 8 objgather + 4 smplsum + 8 smplgather
constexpr int UNITS_PER_B = NBLK_O + P_ + NBLK_S + P_;   // 36
constexpr int NXCD = 8;
constexpr int NSLOT = B_ / NXCD;                         // 32

// 16 B vector with 4 B alignment: lets LLVM emit global_load_dwordx4 from a
// 12 B-strided (dword-aligned) vertex address.
typedef float f32x4a4 __attribute__((ext_vector_type(4), aligned(4)));

#define DEV_INLINE __device__ __forceinline__

DEV_INLINE float wredsum(float v) {
#pragma unroll
    for (int o = 32; o; o >>= 1) v += __shfl_down(v, o);
    return v;
}
DEV_INLINE float wredmin(float v) {
#pragma unroll
    for (int o = 32; o; o >>= 1) v = fminf(v, __shfl_down(v, o));
    return v;
}
DEV_INLINE float wredmax(float v) {
#pragma unroll
    for (int o = 32; o; o >>= 1) v = fmaxf(v, __shfl_down(v, o));
    return v;
}

// ---------------------------------------------------------------------------
// Stream role: per-batch component partial sums (verbatim round-6/8).
// ---------------------------------------------------------------------------
template <int N, int NBLK>
DEV_INLINE void batch_sum_body(const float* __restrict__ v, int b, int blk,
                               float* __restrict__ out) {
    const int chunk = (N + NBLK - 1) / NBLK;
    const int s = blk * chunk;
    const int e = min(N, s + chunk);
    const float* base = v + (size_t)b * N * 3;
    float sx = 0.f, sy = 0.f, sz = 0.f;
    for (int i = s + (int)threadIdx.x; i < e; i += 256) {
        const float* p = base + (size_t)i * 3;
        sx += p[0];
        sy += p[1];
        sz += p[2];
    }
    __shared__ float red[3][4];
    float r0 = wredsum(sx), r1 = wredsum(sy), r2 = wredsum(sz);
    const int lane = threadIdx.x & 63, wv = threadIdx.x >> 6;
    if (lane == 0) { red[0][wv] = r0; red[1][wv] = r1; red[2][wv] = r2; }
    __syncthreads();
    if (threadIdx.x == 0) {
        float* o = out + ((size_t)b * NBLK + blk) * 3;
        o[0] = red[0][0] + red[0][1] + red[0][2] + red[0][3];
        o[1] = red[1][0] + red[1][1] + red[1][2] + red[1][3];
        o[2] = red[2][0] + red[2][1] + red[2][2] + red[2][3];
    }
}

// ---------------------------------------------------------------------------
// Gather role: per-(batch,part) statistics. Same math/order as round 6/8;
// each vertex fetched with ONE dwordx4 load. Only the global-last vertex
// (b == B_-1 && id == N-1) would read 4 B past the buffer: load shifted by
// -1 float and select components (wave-uniform batch check hoists).
// ---------------------------------------------------------------------------
template <int N, int K>
DEV_INLINE void part_stats_body(const float* __restrict__ v,
                                const int* __restrict__ pidx,
                                const float* __restrict__ Ks, int b, int p,
                                float* __restrict__ out) {
    const float fx = Ks[b * 9 + 0];
    const float cx = Ks[b * 9 + 2];
    const float fy = Ks[b * 9 + 4];
    const float cy = Ks[b * 9 + 5];
    const float* base = v + (size_t)b * N * 3;
    const int* idx = pidx + (size_t)p * K;
    const bool lastBatch = (b == B_ - 1);

    constexpr int ITER = K / 256;
    int ids[ITER];
#pragma unroll
    for (int j = 0; j < ITER; ++j) ids[j] = idx[threadIdx.x + j * 256];

    float vx[ITER], vy[ITER], vz[ITER];
#pragma unroll
    for (int j = 0; j < ITER; ++j) {
        const bool shift = lastBatch && (ids[j] == N - 1);
        const float* vp = base + (size_t)ids[j] * 3 - (shift ? 1 : 0);
        const f32x4a4 f = *reinterpret_cast<const f32x4a4*>(vp);
        vx[j] = shift ? f.y : f.x;
        vy[j] = shift ? f.z : f.y;
        vz[j] = shift ? f.w : f.z;
    }

    float umin = INFINITY, umax = -INFINITY, wmin = INFINITY, wmax = -INFINITY;
    float zmin = INFINITY, zmax = -INFINITY;
    float sx = 0.f, sy = 0.f, sz = 0.f;
#pragma unroll
    for (int j = 0; j < ITER; ++j) {
        const float x = vx[j], y = vy[j], z = vz[j];
        sx += x; sy += y; sz += z;
        zmin = fminf(zmin, z); zmax = fmaxf(zmax, z);
        float u, w;
        {
#pragma clang fp contract(off)
            const float zd = z + EPS_;
            const float x_ = x / zd;
            const float y_ = (-y) / zd;
            u = fx * x_ + cx;
            w = 1.0f - (fy * y_ + cy);
            u = 2.0f * (u - 0.5f);
            w = 2.0f * (w - 0.5f);
        }
        umin = fminf(umin, u); umax = fmaxf(umax, u);
        wmin = fminf(wmin, w); wmax = fmaxf(wmax, w);
    }

    __shared__ float red[4][9];
    float r[9];
    r[0] = wredmin(umin); r[1] = wredmax(umax);
    r[2] = wredmin(wmin); r[3] = wredmax(wmax);
    r[4] = wredmin(zmin); r[5] = wredmax(zmax);
    r[6] = wredsum(sx);   r[7] = wredsum(sy); r[8] = wredsum(sz);
    const int lane = threadIdx.x & 63, wv = threadIdx.x >> 6;
    if (lane == 0) {
#pragma unroll
        for (int q = 0; q < 9; ++q) red[wv][q] = r[q];
    }
    __syncthreads();
    if (threadIdx.x == 0) {
        float* o = out + ((size_t)b * P_ + p) * 9;
        o[0] = fminf(fminf(red[0][0], red[1][0]), fminf(red[2][0], red[3][0]));
        o[1] = fmaxf(fmaxf(red[0][1], red[1][1]), fmaxf(red[2][1], red[3][1]));
        o[2] = fminf(fminf(red[0][2], red[1][2]), fminf(red[2][2], red[3][2]));
        o[3] = fmaxf(fmaxf(red[0][3], red[1][3]), fmaxf(red[2][3], red[3][3]));
        o[4] = fminf(fminf(red[0][4], red[1][4]), fminf(red[2][4], red[3][4]));
        o[5] = fmaxf(fmaxf(red[0][5], red[1][5]), fmaxf(red[2][5], red[3][5]));
        o[6] = red[0][6] + red[1][6] + red[2][6] + red[3][6];
        o[7] = red[0][7] + red[1][7] + red[2][7] + red[3][7];
        o[8] = red[0][8] + red[1][8] + red[2][8] + red[3][8];
    }
}

// ---------------------------------------------------------------------------
// Phase 1: gid -> xcd = gid&7, unit = gid>>3, slot = unit/36, role = unit%36.
// Stream roles use batch slot*8+xcd; gather roles use the previous slot's
// batch on the same XCD (round-8 mapping).
// role: [0,16) objsum | [16,24) objgather | [24,28) smplsum | [28,36) smplgather
// ---------------------------------------------------------------------------
__global__ __launch_bounds__(256) void phase1_kernel(
        const float* __restrict__ obj, const float* __restrict__ smpl,
        const float* __restrict__ Ks,
        const int* __restrict__ sidx, const int* __restrict__ oidx,
        float* __restrict__ sumO, float* __restrict__ sumS,
        float* __restrict__ statsO, float* __restrict__ statsS) {
    const int gid = blockIdx.x;
    const int xcd = gid & (NXCD - 1);
    const int unit = gid >> 3;
    const int slot = unit / UNITS_PER_B;
    const int role = unit % UNITS_PER_B;
    const int bs = slot * NXCD + xcd;                        // stream batch
    const int bg = ((slot + NSLOT - 1) & (NSLOT - 1)) * NXCD + xcd; // gather batch
    if (role < NBLK_O) {
        batch_sum_body<NO_, NBLK_O>(obj, bs, role, sumO);
    } else if (role < NBLK_O + P_) {
        part_stats_body<NO_, KO_>(obj, oidx, Ks, bg, role - NBLK_O, statsO);
    } else if (role < NBLK_O + P_ + NBLK_S) {
        batch_sum_body<NS_, NBLK_S>(smpl, bs, role - (NBLK_O + P_), sumS);
    } else {
        part_stats_body<NS_, KS_>(smpl, sidx, Ks, bg, role - (NBLK_O + P_ + NBLK_S), statsS);
    }
}

// ---------------------------------------------------------------------------
// Kernel D: per-batch pair masking + partial sums (verbatim round-2/6/8).
// ---------------------------------------------------------------------------
__global__ __launch_bounds__(64) void pair_kernel(
        const float* __restrict__ statsS, const float* __restrict__ statsO,
        float* __restrict__ partial) {
#pragma clang fp contract(off)
    const int b = blockIdx.x;
    __shared__ float sS[P_][9];
    __shared__ float sO[P_][9];
    const int t = threadIdx.x;
    for (int i = t; i < 2 * P_ * 9; i += 64) {
        if (i < P_ * 9) sS[i / 9][i % 9] = statsS[(size_t)b * P_ * 9 + i];
        else {
            const int u = i - P_ * 9;
            sO[u / 9][u % 9] = statsO[(size_t)b * P_ * 9 + u];
        }
    }
    __syncthreads();

    const int ps = t >> 3;
    const int po = t & 7;

    const float* ssp = sS[po];
    const float* sop = sO[po];
    const float pcu = (ssp[0] + ssp[1]) * 0.5f;
    const float phu = (ssp[1] - ssp[0]) * 0.5f * 1.5f;
    const float pcw = (ssp[2] + ssp[3]) * 0.5f;
    const float phw = (ssp[3] - ssp[2]) * 0.5f * 1.5f;
    const float px0 = pcu - phu, px1 = pcu + phu;
    const float py0 = pcw - phw, py1 = pcw + phw;
    const float ocu = (sop[0] + sop[1]) * 0.5f;
    const float ohu = (sop[1] - sop[0]) * 0.5f * 1.5f;
    const float ocw = (sop[2] + sop[3]) * 0.5f;
    const float ohw = (sop[3] - sop[2]) * 0.5f * 1.5f;
    const float ox0 = ocu - ohu, ox1 = ocu + ohu;
    const float oy0 = ocw - ohw, oy1 = ocw + ohw;
    const bool ov = !((ox0 > px1) || (px0 > ox1) || (oy0 > py1) || (py0 > oy1));

    const float a  = sS[ps][4];
    const float bm = sS[ps][5];
    const float c  = sO[po][4];
    const float d  = sO[po][5];
    const float gap = fminf(fabsf(c - bm), fabsf(a - d));
    const float zd = ((d >= a) && (bm >= c)) ? 0.f : gap;
    const bool m = ov && (zd < ZTH_);

    const float ms0 = sS[ps][6] / (float)KS_;
    const float ms1 = sS[ps][7] / (float)KS_;
    const float ms2 = sS[ps][8] / (float)KS_;
    const float mo0 = sO[po][6] / (float)KO_;
    const float mo1 = sO[po][7] / (float)KO_;
    const float mo2 = sO[po][8] / (float)KO_;
    const float d0 = ms0 - mo0, d1 = ms1 - mo1, d2 = ms2 - mo2;
    const float pm = (d0 * d0 + d1 * d1 + d2 * d2) / 3.0f;

    float psum = m ? pm : 0.f;
    float pcnt = m ? 1.f : 0.f;
    psum = wredsum(psum);
    pcnt = wredsum(pcnt);
    if (t == 0) {
        partial[(size_t)b * 2 + 0] = psum;
        partial[(size_t)b * 2 + 1] = pcnt;
    }
}

// ---------------------------------------------------------------------------
// Kernel E: loss_inter + final reduce (verbatim round-6/8).
// ---------------------------------------------------------------------------
__global__ __launch_bounds__(256) void last_kernel(
        const float* __restrict__ sumS, const float* __restrict__ sumO,
        const float* __restrict__ pairPartial, float* __restrict__ out) {
    const int t = threadIdx.x;
    float d2 = 0.f;
#pragma unroll
    for (int c = 0; c < 3; ++c) {
        float ss = 0.f, so = 0.f;
#pragma unroll
        for (int k = 0; k < NBLK_S; ++k) ss += sumS[((size_t)t * NBLK_S + k) * 3 + c];
#pragma unroll
        for (int k = 0; k < NBLK_O; ++k) so += sumO[((size_t)t * NBLK_O + k) * 3 + c];
        const float ms = ss / (float)NS_;
        const float mo = so / (float)NO_;
        const float d = ms - mo;
        d2 += d * d;
    }
    float s = pairPartial[(size_t)t * 2 + 0];
    float c2 = pairPartial[(size_t)t * 2 + 1];
    __shared__ float rli[4], rs[4], rc[4];
    const float rl = wredsum(d2);
    const float ss2 = wredsum(s);
    const float cc = wredsum(c2);
    const int lane = t & 63, wv = t >> 6;
    if (lane == 0) { rli[wv] = rl; rs[wv] = ss2; rc[wv] = cc; }
    __syncthreads();
    if (t == 0) {
        const float tot = rli[0] + rli[1] + rli[2] + rli[3];
        out[0] = tot / (3.0f * (float)B_) / (float)B_;
        const float S = rs[0] + rs[1] + rs[2] + rs[3];
        const float C = rc[0] + rc[1] + rc[2] + rc[3];
        out[1] = (C > 0.f) ? (S / C) : 0.f;
    }
}

// ---------------------------------------------------------------------------
extern "C" void kernel_launch(void* const* d_in, const int* in_sizes, int n_in,
                              void* d_out, int out_size, void* d_ws, size_t ws_size,
                              hipStream_t stream) {
    const float* smpl = (const float*)d_in[0];
    const float* obj  = (const float*)d_in[1];
    const float* Ks   = (const float*)d_in[2];
    const int*   sidx = (const int*)d_in[3];
    const int*   oidx = (const int*)d_in[4];
    float* out = (float*)d_out;

    float* w = (float*)d_ws;
    float* sumO   = w;                                 // 256*16*3 = 12288
    float* sumS   = sumO + (size_t)B_ * NBLK_O * 3;    // 256*4*3  = 3072
    float* statsS = sumS + (size_t)B_ * NBLK_S * 3;    // 256*8*9  = 18432
    float* statsO = statsS + (size_t)B_ * P_ * 9;      // 256*8*9  = 18432
    float* pairP  = statsO + (size_t)B_ * P_ * 9;      // 512

    phase1_kernel<<<B_ * UNITS_PER_B, 256, 0, stream>>>(
        obj, smpl, Ks, sidx, oidx, sumO, sumS, statsO, statsS);
    pair_kernel<<<B_, 64, 0, stream>>>(statsS, statsO, pairP);
    last_kernel<<<1, 256, 0, stream>>>(sumS, sumO, pairP, out);
}